// Round 5
// baseline (241.285 us; speedup 1.0000x reference)
//
#include <hip/hip_runtime.h>
#include <hip/hip_bf16.h>

#define B_ 4
#define T_ 2048
#define D_ 1024
#define N_ 16
#define TCH 32     // timesteps per chunk
#define NCH 64     // number of chunks (TCH*NCH == T_)

typedef __attribute__((ext_vector_type(4))) float f32x4;
typedef __attribute__((ext_vector_type(8))) short short8;
typedef unsigned int u32;
typedef unsigned short u16;

#if defined(__has_builtin)
#if __has_builtin(__builtin_amdgcn_exp2f)
#define EXP2(x) __builtin_amdgcn_exp2f(x)
#else
#define EXP2(x) exp2f(x)
#endif
#else
#define EXP2(x) exp2f(x)
#endif

__device__ __forceinline__ float softplus_f(float v) {
    return v > 20.f ? v : log1pf(__expf(v));
}

// f32 -> bf16 round-to-nearest-even
__device__ __forceinline__ u16 f2bf(float f) {
    u32 u = __float_as_uint(f);
    u32 r = (u + 0x7fffu + ((u >> 16) & 1u)) >> 16;
    return (u16)r;
}

// ---------------- convert f32 -> bf16 (vectorized) ----------------
__global__ __launch_bounds__(256) void cvt_f32_bf16(const float* __restrict__ in,
                                                    u16* __restrict__ out, int n4) {
    int i = blockIdx.x * 256 + threadIdx.x;
    if (i >= n4) return;
    float4 v = ((const float4*)in)[i];
    ushort4 o;
    o.x = f2bf(v.x); o.y = f2bf(v.y); o.z = f2bf(v.z); o.w = f2bf(v.w);
    ((ushort4*)out)[i] = o;
}

__device__ __forceinline__ void gload_lds16(const void* g, void* l) {
    __builtin_amdgcn_global_load_lds((const __attribute__((address_space(1))) u32*)g,
                                     (__attribute__((address_space(3))) u32*)l, 16, 0, 0);
}

// ---------------- bf16 GEMM, C[m,n] = sum_k A[m,k]*Bw[n,k]  (+bias, opt softplus)
// 256x128 tile, 8 waves (4Mx2N), BK=64, THREE LDS buffers (144 KB), counted
// vmcnt(12) pipeline (tiles t / t+1 / t+2 in flight; never drains to 0 in the
// main loop), raw s_barrier (no __syncthreads -> no forced vmcnt(0) drain).
// XOR bank-swizzle via pre-swizzled global source (rule #21). Grid 256 blocks
// = 1 block/CU; A-panel sharers are XCD-local (ids differ by 32 = 0 mod 8).
template <int ACT>
__global__ __launch_bounds__(512, 2) void gemm_bt(const u16* __restrict__ A,   // [M,K] bf16
                                                  const u16* __restrict__ Bw,  // [N,K] bf16
                                                  const float* __restrict__ bias, // [N]
                                                  float* __restrict__ C,       // [M,N] f32
                                                  int M, int N, int K) {
    __shared__ __align__(16) u16 sA[3][256 * 64];   // 3 x 32 KB
    __shared__ __align__(16) u16 sB[3][128 * 64];   // 3 x 16 KB
    const int tid = threadIdx.x;
    const int wid = tid >> 6;       // 0..7
    const int lane = tid & 63;
    const int m0 = blockIdx.x * 256;
    const int n0 = blockIdx.y * 128;
    const int wm = wid >> 1;        // 0..3 : 64-row group
    const int wn = wid & 1;         // 0..1 : 64-col group

    // staging geometry: segment = 8 rows x 128 B = 1 KB, one gload_lds16 each.
    // A-tile: 32 segs (r=0..3), B-tile: 16 segs (r=0..1); wave w takes seg w+8r.
    const int lrow = lane >> 3;
    const int slot = lane & 7;
    const int ksw = (slot ^ lrow) << 3;   // pre-swizzled k offset (elements)

    const u16* aSrc[4]; int aOff[4];
    #pragma unroll
    for (int r = 0; r < 4; ++r) {
        const int seg = wid + r * 8;                   // 0..31
        aOff[r] = seg * 1024;
        aSrc[r] = A + (size_t)(m0 + seg * 8 + lrow) * K + ksw;
    }
    const u16* bSrc[2]; int bOff[2];
    #pragma unroll
    for (int r = 0; r < 2; ++r) {
        const int sb = wid + r * 8;                    // 0..15
        bOff[r] = sb * 1024;
        bSrc[r] = Bw + (size_t)(n0 + sb * 8 + lrow) * K + ksw;
    }

    f32x4 acc[4][4] = {};
    const int fr = lane & 15;
    const int g = lane >> 4;
    const int xorv = (fr & 7) << 4;
    const int nt = K / 64;   // 16

    auto STAGE = [&](int t) {   // 6 gload_lds16 per wave
        const int bf = t % 3;
        const int k0 = t * 64;
        #pragma unroll
        for (int r = 0; r < 4; ++r)
            gload_lds16(aSrc[r] + k0, (char*)sA[bf] + aOff[r]);
        #pragma unroll
        for (int r = 0; r < 2; ++r)
            gload_lds16(bSrc[r] + k0, (char*)sB[bf] + bOff[r]);
    };
    auto COMP = [&](int t) {
        const int bf = t % 3;
        const char* bA = (const char*)sA[bf];
        const char* bB = (const char*)sB[bf];
        #pragma unroll
        for (int kk = 0; kk < 2; ++kk) {
            const int ksb = (kk * 64 + g * 16) ^ xorv;   // swizzled k-byte
            short8 af[4], bv[4];
            #pragma unroll
            for (int f = 0; f < 4; ++f) {
                af[f] = *(const short8*)(bA + (wm * 64 + f * 16 + fr) * 128 + ksb);
                bv[f] = *(const short8*)(bB + (wn * 64 + f * 16 + fr) * 128 + ksb);
            }
            __builtin_amdgcn_s_setprio(1);
            #pragma unroll
            for (int i = 0; i < 4; ++i)
                #pragma unroll
                for (int j = 0; j < 4; ++j)
                    acc[i][j] = __builtin_amdgcn_mfma_f32_16x16x32_bf16(af[i], bv[j],
                                                                        acc[i][j], 0, 0, 0);
            __builtin_amdgcn_s_setprio(0);
        }
    };

    // prologue: tiles 0 and 1 in flight (12 outstanding loads per wave)
    STAGE(0);
    STAGE(1);
    // main loop: keep 3 tiles in flight, wait only for the oldest (vmcnt(12))
    for (int t = 0; t < nt - 2; ++t) {
        STAGE(t + 2);                                      // 18 outstanding
        asm volatile("s_waitcnt vmcnt(12)" ::: "memory");  // tile t landed (this wave)
        __builtin_amdgcn_s_barrier();                      // all waves' tile-t parts in LDS
        asm volatile("" ::: "memory");
        COMP(t);
        __builtin_amdgcn_s_barrier();                      // tile-t LDS free for reuse
        asm volatile("" ::: "memory");
    }
    // tails: nt-2 (6 newer outstanding), nt-1 (drain)
    asm volatile("s_waitcnt vmcnt(6)" ::: "memory");
    __builtin_amdgcn_s_barrier();
    asm volatile("" ::: "memory");
    COMP(nt - 2);
    __builtin_amdgcn_s_barrier();
    asm volatile("" ::: "memory");
    asm volatile("s_waitcnt vmcnt(0)" ::: "memory");
    __builtin_amdgcn_s_barrier();
    asm volatile("" ::: "memory");
    COMP(nt - 1);

    // epilogue: C/D layout col=lane&15, row=(lane>>4)*4+reg (m89-verified)
    const int cl = lane & 15;
    const int rg = (lane >> 4) * 4;
    #pragma unroll
    for (int j = 0; j < 4; ++j) {
        const int col = n0 + wn * 64 + j * 16 + cl;
        const float bv = bias[col];
        #pragma unroll
        for (int i = 0; i < 4; ++i) {
            #pragma unroll
            for (int r = 0; r < 4; ++r) {
                const int rowg = m0 + wm * 64 + i * 16 + rg + r;
                float v = acc[i][j][r] + bv;
                if (ACT) v = softplus_f(v);
                C[(size_t)rowg * N + col] = v;
            }
        }
    }
}

// ---------------- scan phase 1: per-chunk local scan (zero init) ----------------
__global__ __launch_bounds__(256) void scan_p1(const float* __restrict__ delta,
                                               const float* __restrict__ x,
                                               const float* __restrict__ a_log,
                                               float* __restrict__ S,       // [NCH,B,D,N]
                                               float* __restrict__ dtsum) { // [NCH,B,D]
    const int gid = blockIdx.x * 256 + threadIdx.x;
    const int d = gid & (D_ - 1);
    const int cb = gid >> 10;
    const int b = cb & (B_ - 1);
    const int c = cb >> 2;

    float an2[N_];
    const float4* a4 = (const float4*)&a_log[d * N_];
    #pragma unroll
    for (int q = 0; q < 4; ++q) {
        float4 av = a4[q];
        an2[q * 4 + 0] = (softplus_f(av.x) + 1e-4f) * 1.44269504f;
        an2[q * 4 + 1] = (softplus_f(av.y) + 1e-4f) * 1.44269504f;
        an2[q * 4 + 2] = (softplus_f(av.z) + 1e-4f) * 1.44269504f;
        an2[q * 4 + 3] = (softplus_f(av.w) + 1e-4f) * 1.44269504f;
    }

    float s[N_];
    #pragma unroll
    for (int n = 0; n < N_; ++n) s[n] = 0.f;
    float dts = 0.f;

    const size_t base = ((size_t)b * T_ + (size_t)c * TCH) * D_ + d;
    for (int i = 0; i < TCH; ++i) {
        const float dt = delta[base + (size_t)i * D_];
        const float xv = x[base + (size_t)i * D_];
        const float dtx = dt * xv;
        dts += dt;
        #pragma unroll
        for (int n = 0; n < N_; ++n) {
            const float ab = EXP2(-dt * an2[n]);
            s[n] = fmaf(ab, s[n], dtx);
        }
    }

    float* So = &S[(size_t)gid * N_];
    #pragma unroll
    for (int n = 0; n < N_; ++n) So[n] = s[n];
    dtsum[gid] = dts;
}

// ---------------- scan phase 2: 64-step carry scan across chunks ----------------
__global__ __launch_bounds__(256) void scan_p2(const float* __restrict__ S,
                                               const float* __restrict__ dtsum,
                                               const float* __restrict__ a_log,
                                               float* __restrict__ carry_out) {
    const int gid = blockIdx.x * 256 + threadIdx.x;
    const int n = gid & 15;
    const int d = (gid >> 4) & (D_ - 1);
    const int b = gid >> 14;
    const float an2 = (softplus_f(a_log[d * N_ + n]) + 1e-4f) * 1.44269504f;
    float carry = 0.f;
    for (int c = 0; c < NCH; ++c) {
        const size_t cb = (size_t)c * B_ + b;
        const size_t idx = (cb * D_ + d) * N_ + n;
        carry_out[idx] = carry;                       // carry INTO chunk c
        const float dts = dtsum[cb * D_ + d];
        const float P = EXP2(-dts * an2);             // prod of a_bar over chunk
        carry = fmaf(P, carry, S[idx]);
    }
}

// ---------------- scan phase 3: replay with true carry, emit y (bf16) ----------------
__global__ __launch_bounds__(256) void scan_p3(const float* __restrict__ delta,
                                               const float* __restrict__ x,
                                               const float* __restrict__ a_log,
                                               const float* __restrict__ b_param,
                                               const float* __restrict__ carry_in,
                                               u16* __restrict__ y) {  // [B,T,D] bf16
    const int gid = blockIdx.x * 256 + threadIdx.x;
    const int d = gid & (D_ - 1);
    const int cb = gid >> 10;
    const int b = cb & (B_ - 1);
    const int c = cb >> 2;

    float an2[N_], bp[N_];
    const float4* a4 = (const float4*)&a_log[d * N_];
    const float4* b4 = (const float4*)&b_param[d * N_];
    #pragma unroll
    for (int q = 0; q < 4; ++q) {
        float4 av = a4[q];
        float4 bv = b4[q];
        an2[q * 4 + 0] = (softplus_f(av.x) + 1e-4f) * 1.44269504f;
        an2[q * 4 + 1] = (softplus_f(av.y) + 1e-4f) * 1.44269504f;
        an2[q * 4 + 2] = (softplus_f(av.z) + 1e-4f) * 1.44269504f;
        an2[q * 4 + 3] = (softplus_f(av.w) + 1e-4f) * 1.44269504f;
        bp[q * 4 + 0] = bv.x; bp[q * 4 + 1] = bv.y;
        bp[q * 4 + 2] = bv.z; bp[q * 4 + 3] = bv.w;
    }

    float s[N_];
    const float* ci = &carry_in[(size_t)gid * N_];
    #pragma unroll
    for (int n = 0; n < N_; ++n) s[n] = ci[n];

    const size_t base = ((size_t)b * T_ + (size_t)c * TCH) * D_ + d;
    for (int i = 0; i < TCH; ++i) {
        const float dt = delta[base + (size_t)i * D_];
        const float xv = x[base + (size_t)i * D_];
        const float dtx = dt * xv;
        float acc = 0.f;
        #pragma unroll
        for (int n = 0; n < N_; ++n) {
            const float ab = EXP2(-dt * an2[n]);
            s[n] = fmaf(ab, s[n], dtx);
            acc = fmaf(bp[n], s[n], acc);
        }
        y[base + (size_t)i * D_] = f2bf(acc);
    }
}

// ---------------- launch ----------------
extern "C" void kernel_launch(void* const* d_in, const int* in_sizes, int n_in,
                              void* d_out, int out_size, void* d_ws, size_t ws_size,
                              hipStream_t stream) {
    const float* x      = (const float*)d_in[0];
    const float* Wd     = (const float*)d_in[1];
    const float* bd     = (const float*)d_in[2];
    const float* a_log  = (const float*)d_in[3];
    const float* b_par  = (const float*)d_in[4];
    const float* Wo     = (const float*)d_in[5];
    const float* bo     = (const float*)d_in[6];
    float* out = (float*)d_out;

    char* ws = (char*)d_ws;
    // region A (16 MB): x_bf16 during GEMM1, then carry_in for scan p2/p3
    u16*   xbf     = (u16*)(ws);
    float* carry   = (float*)(ws);
    // region B (16 MB): S during p1/p2, then y_bf16 for p3/GEMM2
    float* S       = (float*)(ws + 16777216);
    u16*   ybf     = (u16*)(ws + 16777216);
    float* delta   = (float*)(ws + 33554432);          // 32 MB
    u16*   wdbf    = (u16*)(ws + 67108864);            // 2 MB
    u16*   wobf    = (u16*)(ws + 69206016);            // 2 MB
    float* dtsum   = (float*)(ws + 71303168);          // 1 MB
    (void)in_sizes; (void)n_in; (void)out_size; (void)ws_size;

    const int M = B_ * T_;  // 8192

    // convert inputs to bf16
    cvt_f32_bf16<<<(M * D_ / 4 + 255) / 256, 256, 0, stream>>>(x, xbf, M * D_ / 4);
    cvt_f32_bf16<<<(D_ * D_ / 4 + 255) / 256, 256, 0, stream>>>(Wd, wdbf, D_ * D_ / 4);
    cvt_f32_bf16<<<(D_ * D_ / 4 + 255) / 256, 256, 0, stream>>>(Wo, wobf, D_ * D_ / 4);

    // delta = softplus(x @ Wd^T + bd)
    gemm_bt<1><<<dim3(M / 256, D_ / 128), 512, 0, stream>>>(xbf, wdbf, bd, delta, M, D_, D_);

    // blocked scan
    scan_p1<<<NCH * B_ * D_ / 256, 256, 0, stream>>>(delta, x, a_log, S, dtsum);
    scan_p2<<<B_ * D_ * N_ / 256, 256, 0, stream>>>(S, dtsum, a_log, carry);
    scan_p3<<<NCH * B_ * D_ / 256, 256, 0, stream>>>(delta, x, a_log, b_par, carry, ybf);

    // out = y @ Wo^T + bo
    gemm_bt<0><<<dim3(M / 256, D_ / 128), 512, 0, stream>>>(ybf, wobf, bo, out, M, D_, D_);
}

// Round 6
// 221.537 us; speedup vs baseline: 1.0891x; 1.0891x over previous
//
#include <hip/hip_runtime.h>
#include <hip/hip_bf16.h>

#define B_ 4
#define T_ 2048
#define D_ 1024
#define N_ 16
#define TCH 32     // timesteps per chunk
#define NCH 64     // number of chunks (TCH*NCH == T_)

typedef __attribute__((ext_vector_type(4))) float f32x4;
typedef __attribute__((ext_vector_type(8))) short short8;
typedef unsigned int u32;
typedef unsigned short u16;

#if defined(__has_builtin)
#if __has_builtin(__builtin_amdgcn_exp2f)
#define EXP2(x) __builtin_amdgcn_exp2f(x)
#else
#define EXP2(x) exp2f(x)
#endif
#else
#define EXP2(x) exp2f(x)
#endif

__device__ __forceinline__ float softplus_f(float v) {
    return v > 20.f ? v : log1pf(__expf(v));
}

// f32 -> bf16 round-to-nearest-even
__device__ __forceinline__ u16 f2bf(float f) {
    u32 u = __float_as_uint(f);
    u32 r = (u + 0x7fffu + ((u >> 16) & 1u)) >> 16;
    return (u16)r;
}

// ---------------- convert f32 -> bf16 (vectorized) ----------------
__global__ __launch_bounds__(256) void cvt_f32_bf16(const float* __restrict__ in,
                                                    u16* __restrict__ out, int n4) {
    int i = blockIdx.x * 256 + threadIdx.x;
    if (i >= n4) return;
    float4 v = ((const float4*)in)[i];
    ushort4 o;
    o.x = f2bf(v.x); o.y = f2bf(v.y); o.z = f2bf(v.z); o.w = f2bf(v.w);
    ((ushort4*)out)[i] = o;
}

// ---------------- bf16 GEMM, C[m,n] = sum_k A[m,k]*Bw[n,k]  (+bias, opt softplus)
// R3 structure (128x128 tile, BK=64, 4 waves 2x2, double-buffered LDS, XOR
// swizzle) with staging mechanism swapped: REG-STAGING (global_load_dwordx4 ->
// VGPR -> linear ds_write_b128) instead of global_load_lds. Loads for tile
// t+2 are issued one full compute-phase before their ds_write (T14 split).
// Swizzle scheme (verified in R3, 0 conflicts): pre-swizzled global source +
// linear LDS write + XOR'd ds_read address.
#define BM 128
#define BN 128
#define BK 64

template <int ACT>
__global__ __launch_bounds__(256, 2) void gemm_bt(const u16* __restrict__ A,   // [M,K] bf16
                                                  const u16* __restrict__ Bw,  // [N,K] bf16
                                                  const float* __restrict__ bias, // [N]
                                                  float* __restrict__ C,       // [M,N] f32
                                                  int M, int N, int K) {
    __shared__ __align__(16) u16 sA[2][BM * BK];   // 2 x 16 KB
    __shared__ __align__(16) u16 sB[2][BN * BK];   // 2 x 16 KB
    const int tid = threadIdx.x;
    const int wid = tid >> 6;
    const int lane = tid & 63;
    const int m0 = blockIdx.x * BM;
    const int n0 = blockIdx.y * BN;
    const int wm = wid >> 1, wn = wid & 1;  // 2x2 wave grid, each wave 64x64

    // staging geometry: 16 segments of 8 rows x 128B per matrix; wave handles
    // segs wid, wid+4, wid+8, wid+12. lane -> (row=lane>>3, slot=lane&7).
    const int lrow = lane >> 3;
    const int slot = lane & 7;
    const int ksw = (slot ^ lrow) << 3;  // pre-swizzled source k-offset (elems)

    size_t aRow[4], bRow[4];
    int dsOf[4];
    #pragma unroll
    for (int r = 0; r < 4; ++r) {
        const int seg = r * 4 + wid;
        const int row = seg * 8 + lrow;
        aRow[r] = (size_t)(m0 + row) * K + ksw;
        bRow[r] = (size_t)(n0 + row) * K + ksw;
        dsOf[r] = seg * 1024 + lrow * 128 + slot * 16;  // linear per-lane byte offset
    }

    short8 ra[4], rb[4];   // in-flight staging registers (32 VGPRs)
    f32x4 acc[4][4] = {};

    const int nt = K / BK;   // 16
    const int fr = lane & 15;
    const int g = lane >> 4;
    const int xorv = (fr & 7) << 4;

    // prologue: tile 0 -> LDS buf0; tile 1 loads in flight
    #pragma unroll
    for (int r = 0; r < 4; ++r) ra[r] = *(const short8*)(A + aRow[r]);
    #pragma unroll
    for (int r = 0; r < 4; ++r) rb[r] = *(const short8*)(Bw + bRow[r]);
    #pragma unroll
    for (int r = 0; r < 4; ++r) *(short8*)((char*)sA[0] + dsOf[r]) = ra[r];
    #pragma unroll
    for (int r = 0; r < 4; ++r) *(short8*)((char*)sB[0] + dsOf[r]) = rb[r];
    #pragma unroll
    for (int r = 0; r < 4; ++r) ra[r] = *(const short8*)(A + aRow[r] + BK);
    #pragma unroll
    for (int r = 0; r < 4; ++r) rb[r] = *(const short8*)(Bw + bRow[r] + BK);
    __syncthreads();

    for (int t = 0; t < nt; ++t) {
        // ---- compute tile t from LDS buf t&1 ----
        const char* bA = (const char*)sA[t & 1];
        const char* bB = (const char*)sB[t & 1];
        #pragma unroll
        for (int kk = 0; kk < 2; ++kk) {
            const int ksb = (kk * 64 + g * 16) ^ xorv;  // swizzled k-byte
            short8 af[4], bf[4];
            #pragma unroll
            for (int f = 0; f < 4; ++f) {
                af[f] = *(const short8*)(bA + (wm * 64 + f * 16 + fr) * 128 + ksb);
                bf[f] = *(const short8*)(bB + (wn * 64 + f * 16 + fr) * 128 + ksb);
            }
            __builtin_amdgcn_s_setprio(1);
            #pragma unroll
            for (int i = 0; i < 4; ++i)
                #pragma unroll
                for (int j = 0; j < 4; ++j)
                    acc[i][j] = __builtin_amdgcn_mfma_f32_16x16x32_bf16(af[i], bf[j],
                                                                        acc[i][j], 0, 0, 0);
            __builtin_amdgcn_s_setprio(0);
        }

        if (t + 1 < nt) {
            __syncthreads();   // all waves done reading buf (t+1)&1 (from tile t-1)
            // write tile t+1 (regs, issued one compute-phase ago) to LDS
            const int nb = (t + 1) & 1;
            #pragma unroll
            for (int r = 0; r < 4; ++r) *(short8*)((char*)sA[nb] + dsOf[r]) = ra[r];
            #pragma unroll
            for (int r = 0; r < 4; ++r) *(short8*)((char*)sB[nb] + dsOf[r]) = rb[r];
            // issue loads for tile t+2 (land during compute of t+1)
            if (t + 2 < nt) {
                const int k0 = (t + 2) * BK;
                #pragma unroll
                for (int r = 0; r < 4; ++r) ra[r] = *(const short8*)(A + aRow[r] + k0);
                #pragma unroll
                for (int r = 0; r < 4; ++r) rb[r] = *(const short8*)(Bw + bRow[r] + k0);
            }
            __syncthreads();   // tile t+1 visible in LDS
        }
    }

    // epilogue: C/D layout col=lane&15, row=(lane>>4)*4+reg (m89-verified)
    const int cl = lane & 15;
    const int rg = (lane >> 4) * 4;
    #pragma unroll
    for (int j = 0; j < 4; ++j) {
        const int col = n0 + wn * 64 + j * 16 + cl;
        const float bv = bias[col];
        #pragma unroll
        for (int i = 0; i < 4; ++i) {
            #pragma unroll
            for (int r = 0; r < 4; ++r) {
                const int rowg = m0 + wm * 64 + i * 16 + rg + r;
                float v = acc[i][j][r] + bv;
                if (ACT) v = softplus_f(v);
                C[(size_t)rowg * N + col] = v;
            }
        }
    }
}

// ---------------- scan phase 1: per-chunk local scan (zero init) ----------------
__global__ __launch_bounds__(256) void scan_p1(const float* __restrict__ delta,
                                               const float* __restrict__ x,
                                               const float* __restrict__ a_log,
                                               float* __restrict__ S,       // [NCH,B,D,N]
                                               float* __restrict__ dtsum) { // [NCH,B,D]
    const int gid = blockIdx.x * 256 + threadIdx.x;
    const int d = gid & (D_ - 1);
    const int cb = gid >> 10;
    const int b = cb & (B_ - 1);
    const int c = cb >> 2;

    float an2[N_];
    const float4* a4 = (const float4*)&a_log[d * N_];
    #pragma unroll
    for (int q = 0; q < 4; ++q) {
        float4 av = a4[q];
        an2[q * 4 + 0] = (softplus_f(av.x) + 1e-4f) * 1.44269504f;
        an2[q * 4 + 1] = (softplus_f(av.y) + 1e-4f) * 1.44269504f;
        an2[q * 4 + 2] = (softplus_f(av.z) + 1e-4f) * 1.44269504f;
        an2[q * 4 + 3] = (softplus_f(av.w) + 1e-4f) * 1.44269504f;
    }

    float s[N_];
    #pragma unroll
    for (int n = 0; n < N_; ++n) s[n] = 0.f;
    float dts = 0.f;

    const size_t base = ((size_t)b * T_ + (size_t)c * TCH) * D_ + d;
    for (int i = 0; i < TCH; ++i) {
        const float dt = delta[base + (size_t)i * D_];
        const float xv = x[base + (size_t)i * D_];
        const float dtx = dt * xv;
        dts += dt;
        #pragma unroll
        for (int n = 0; n < N_; ++n) {
            const float ab = EXP2(-dt * an2[n]);
            s[n] = fmaf(ab, s[n], dtx);
        }
    }

    float* So = &S[(size_t)gid * N_];
    #pragma unroll
    for (int n = 0; n < N_; ++n) So[n] = s[n];
    dtsum[gid] = dts;
}

// ---------------- scan phase 2: 64-step carry scan across chunks ----------------
__global__ __launch_bounds__(256) void scan_p2(const float* __restrict__ S,
                                               const float* __restrict__ dtsum,
                                               const float* __restrict__ a_log,
                                               float* __restrict__ carry_out) {
    const int gid = blockIdx.x * 256 + threadIdx.x;
    const int n = gid & 15;
    const int d = (gid >> 4) & (D_ - 1);
    const int b = gid >> 14;
    const float an2 = (softplus_f(a_log[d * N_ + n]) + 1e-4f) * 1.44269504f;
    float carry = 0.f;
    for (int c = 0; c < NCH; ++c) {
        const size_t cb = (size_t)c * B_ + b;
        const size_t idx = (cb * D_ + d) * N_ + n;
        carry_out[idx] = carry;                       // carry INTO chunk c
        const float dts = dtsum[cb * D_ + d];
        const float P = EXP2(-dts * an2);             // prod of a_bar over chunk
        carry = fmaf(P, carry, S[idx]);
    }
}

// ---------------- scan phase 3: replay with true carry, emit y (bf16) ----------------
__global__ __launch_bounds__(256) void scan_p3(const float* __restrict__ delta,
                                               const float* __restrict__ x,
                                               const float* __restrict__ a_log,
                                               const float* __restrict__ b_param,
                                               const float* __restrict__ carry_in,
                                               u16* __restrict__ y) {  // [B,T,D] bf16
    const int gid = blockIdx.x * 256 + threadIdx.x;
    const int d = gid & (D_ - 1);
    const int cb = gid >> 10;
    const int b = cb & (B_ - 1);
    const int c = cb >> 2;

    float an2[N_], bp[N_];
    const float4* a4 = (const float4*)&a_log[d * N_];
    const float4* b4 = (const float4*)&b_param[d * N_];
    #pragma unroll
    for (int q = 0; q < 4; ++q) {
        float4 av = a4[q];
        float4 bv = b4[q];
        an2[q * 4 + 0] = (softplus_f(av.x) + 1e-4f) * 1.44269504f;
        an2[q * 4 + 1] = (softplus_f(av.y) + 1e-4f) * 1.44269504f;
        an2[q * 4 + 2] = (softplus_f(av.z) + 1e-4f) * 1.44269504f;
        an2[q * 4 + 3] = (softplus_f(av.w) + 1e-4f) * 1.44269504f;
        bp[q * 4 + 0] = bv.x; bp[q * 4 + 1] = bv.y;
        bp[q * 4 + 2] = bv.z; bp[q * 4 + 3] = bv.w;
    }

    float s[N_];
    const float* ci = &carry_in[(size_t)gid * N_];
    #pragma unroll
    for (int n = 0; n < N_; ++n) s[n] = ci[n];

    const size_t base = ((size_t)b * T_ + (size_t)c * TCH) * D_ + d;
    for (int i = 0; i < TCH; ++i) {
        const float dt = delta[base + (size_t)i * D_];
        const float xv = x[base + (size_t)i * D_];
        const float dtx = dt * xv;
        float acc = 0.f;
        #pragma unroll
        for (int n = 0; n < N_; ++n) {
            const float ab = EXP2(-dt * an2[n]);
            s[n] = fmaf(ab, s[n], dtx);
            acc = fmaf(bp[n], s[n], acc);
        }
        y[base + (size_t)i * D_] = f2bf(acc);
    }
}

// ---------------- launch ----------------
extern "C" void kernel_launch(void* const* d_in, const int* in_sizes, int n_in,
                              void* d_out, int out_size, void* d_ws, size_t ws_size,
                              hipStream_t stream) {
    const float* x      = (const float*)d_in[0];
    const float* Wd     = (const float*)d_in[1];
    const float* bd     = (const float*)d_in[2];
    const float* a_log  = (const float*)d_in[3];
    const float* b_par  = (const float*)d_in[4];
    const float* Wo     = (const float*)d_in[5];
    const float* bo     = (const float*)d_in[6];
    float* out = (float*)d_out;

    char* ws = (char*)d_ws;
    // region A (16 MB): x_bf16 during GEMM1, then carry_in for scan p2/p3
    u16*   xbf     = (u16*)(ws);
    float* carry   = (float*)(ws);
    // region B (16 MB): S during p1/p2, then y_bf16 for p3/GEMM2
    float* S       = (float*)(ws + 16777216);
    u16*   ybf     = (u16*)(ws + 16777216);
    float* delta   = (float*)(ws + 33554432);          // 32 MB
    u16*   wdbf    = (u16*)(ws + 67108864);            // 2 MB
    u16*   wobf    = (u16*)(ws + 69206016);            // 2 MB
    float* dtsum   = (float*)(ws + 71303168);          // 1 MB
    (void)in_sizes; (void)n_in; (void)out_size; (void)ws_size;

    const int M = B_ * T_;  // 8192

    // convert inputs to bf16
    cvt_f32_bf16<<<(M * D_ / 4 + 255) / 256, 256, 0, stream>>>(x, xbf, M * D_ / 4);
    cvt_f32_bf16<<<(D_ * D_ / 4 + 255) / 256, 256, 0, stream>>>(Wd, wdbf, D_ * D_ / 4);
    cvt_f32_bf16<<<(D_ * D_ / 4 + 255) / 256, 256, 0, stream>>>(Wo, wobf, D_ * D_ / 4);

    // delta = softplus(x @ Wd^T + bd)
    gemm_bt<1><<<dim3(M / BM, D_ / BN), 256, 0, stream>>>(xbf, wdbf, bd, delta, M, D_, D_);

    // blocked scan
    scan_p1<<<NCH * B_ * D_ / 256, 256, 0, stream>>>(delta, x, a_log, S, dtsum);
    scan_p2<<<B_ * D_ * N_ / 256, 256, 0, stream>>>(S, dtsum, a_log, carry);
    scan_p3<<<NCH * B_ * D_ / 256, 256, 0, stream>>>(delta, x, a_log, b_par, carry, ybf);

    // out = y @ Wo^T + bo
    gemm_bt<0><<<dim3(M / BM, D_ / BN), 256, 0, stream>>>(ybf, wobf, bo, out, M, D_, D_);
}

// Round 7
// 172.792 us; speedup vs baseline: 1.3964x; 1.2821x over previous
//
#include <hip/hip_runtime.h>
#include <hip/hip_bf16.h>

#define B_ 4
#define T_ 2048
#define D_ 1024
#define N_ 16
#define TCH 32     // timesteps per chunk
#define NCH 64     // number of chunks (TCH*NCH == T_)

typedef __attribute__((ext_vector_type(4))) float f32x4;
typedef __attribute__((ext_vector_type(8))) short short8;
typedef unsigned int u32;
typedef unsigned short u16;

#if defined(__has_builtin)
#if __has_builtin(__builtin_amdgcn_exp2f)
#define EXP2(x) __builtin_amdgcn_exp2f(x)
#else
#define EXP2(x) exp2f(x)
#endif
#else
#define EXP2(x) exp2f(x)
#endif

__device__ __forceinline__ float softplus_f(float v) {
    return v > 20.f ? v : log1pf(__expf(v));
}

// f32 -> bf16 round-to-nearest-even
__device__ __forceinline__ u16 f2bf(float f) {
    u32 u = __float_as_uint(f);
    u32 r = (u + 0x7fffu + ((u >> 16) & 1u)) >> 16;
    return (u16)r;
}

// ---------------- convert f32 -> bf16 (vectorized) ----------------
__global__ __launch_bounds__(256) void cvt_f32_bf16(const float* __restrict__ in,
                                                    u16* __restrict__ out, int n4) {
    int i = blockIdx.x * 256 + threadIdx.x;
    if (i >= n4) return;
    float4 v = ((const float4*)in)[i];
    ushort4 o;
    o.x = f2bf(v.x); o.y = f2bf(v.y); o.z = f2bf(v.z); o.w = f2bf(v.w);
    ((ushort4*)out)[i] = o;
}

// ---------------- bf16 GEMM, C[m,n] = sum_k A[m,k]*Bw[n,k]  (+bias, opt softplus)
// New axes this round: (1) XCD-local A-slicing — 1-D grid decoded so XCD k
// owns m-panels [8k,8k+8): per-XCD working set = 2 MB A-slice + 2 MB B =
// L2-resident. (2) 16 waves/CU: 512-thread blocks (8 waves, 4x2 grid of
// 32x64 wave tiles), SINGLE 32 KB LDS buffer, reg-staged (global->VGPR->
// ds_write after barrier), t+2 loads issued after the write-barrier so they
// always have a full compute phase of cover. XOR bank-swizzle as verified
// (pre-swizzled source + linear write + XOR'd read; 0 conflicts in R3-R6).
template <int ACT>
__global__ __launch_bounds__(512, 4) void gemm_bt(const u16* __restrict__ A,   // [M,K] bf16
                                                  const u16* __restrict__ Bw,  // [N,K] bf16
                                                  const float* __restrict__ bias, // [N]
                                                  float* __restrict__ C,       // [M,N] f32
                                                  int M, int N, int K) {
    __shared__ __align__(16) u16 sA[128 * 64];   // 16 KB
    __shared__ __align__(16) u16 sB[128 * 64];   // 16 KB
    const int tid = threadIdx.x;
    const int wid = tid >> 6;      // 0..7
    const int lane = tid & 63;

    // XCD-local decode: blocks dispatch round-robin over 8 XCDs by linear id.
    const int wg = blockIdx.x;
    const int xcd = wg & 7;
    const int jj = wg >> 3;
    const int npm8 = (M / 128) >> 3;          // m-panels per XCD (8 for M=8192)
    const int bx = xcd * npm8 + (jj % npm8);  // m-panel
    const int by = jj / npm8;                 // n-panel
    const int m0 = bx * 128;
    const int n0 = by * 128;
    const int wm = wid >> 1;   // 0..3 : 32-row slab
    const int wn = wid & 1;    // 0..1 : 64-col slab

    // staging: 16 segs of 8 rows x 128 B per matrix; wave w takes segs {w, w+8}
    const int lrow = lane >> 3;
    const int slot = lane & 7;
    const int ksw = (slot ^ lrow) << 3;       // pre-swizzled source k-offset

    size_t aRow[2], bRow[2];
    int dsOf[2];
    #pragma unroll
    for (int r = 0; r < 2; ++r) {
        const int seg = wid + r * 8;          // 0..15
        dsOf[r] = seg * 1024 + lrow * 128 + slot * 16;   // linear LDS byte offset
        aRow[r] = (size_t)(m0 + seg * 8 + lrow) * K + ksw;
        bRow[r] = (size_t)(n0 + seg * 8 + lrow) * K + ksw;
    }

    short8 ra[2], rb[2];       // in-flight staging regs (16 VGPRs)
    f32x4 acc[2][4] = {};
    const int nt = K / 64;     // 16
    const int fr = lane & 15;
    const int g = lane >> 4;
    const int xorv = (fr & 7) << 4;

    // prologue: tile 0 -> regs -> LDS; tile 1 -> regs
    #pragma unroll
    for (int r = 0; r < 2; ++r) {
        ra[r] = *(const short8*)(A + aRow[r]);
        rb[r] = *(const short8*)(Bw + bRow[r]);
    }
    #pragma unroll
    for (int r = 0; r < 2; ++r) {
        *(short8*)((char*)sA + dsOf[r]) = ra[r];
        *(short8*)((char*)sB + dsOf[r]) = rb[r];
    }
    #pragma unroll
    for (int r = 0; r < 2; ++r) {
        ra[r] = *(const short8*)(A + aRow[r] + 64);
        rb[r] = *(const short8*)(Bw + bRow[r] + 64);
    }
    asm volatile("s_waitcnt lgkmcnt(0)" ::: "memory");
    __builtin_amdgcn_s_barrier();
    asm volatile("" ::: "memory");

    for (int t = 0; t < nt; ++t) {
        // ---- compute tile t from the single LDS buffer ----
        #pragma unroll
        for (int kk = 0; kk < 2; ++kk) {
            const int ksb = (kk * 64 + g * 16) ^ xorv;   // swizzled k-byte
            short8 af[2], bf[4];
            #pragma unroll
            for (int f = 0; f < 2; ++f)
                af[f] = *(const short8*)((const char*)sA + (wm * 32 + f * 16 + fr) * 128 + ksb);
            #pragma unroll
            for (int f = 0; f < 4; ++f)
                bf[f] = *(const short8*)((const char*)sB + (wn * 64 + f * 16 + fr) * 128 + ksb);
            __builtin_amdgcn_s_setprio(1);
            #pragma unroll
            for (int i = 0; i < 2; ++i)
                #pragma unroll
                for (int j2 = 0; j2 < 4; ++j2)
                    acc[i][j2] = __builtin_amdgcn_mfma_f32_16x16x32_bf16(af[i], bf[j2],
                                                                         acc[i][j2], 0, 0, 0);
            __builtin_amdgcn_s_setprio(0);
        }
        if (t + 1 < nt) {
            asm volatile("s_waitcnt lgkmcnt(0)" ::: "memory");   // my ds_reads done
            __builtin_amdgcn_s_barrier();                        // all waves done reading
            asm volatile("" ::: "memory");
            // write tile t+1 (regs loaded one full phase ago; compiler waits vmcnt)
            #pragma unroll
            for (int r = 0; r < 2; ++r) {
                *(short8*)((char*)sA + dsOf[r]) = ra[r];
                *(short8*)((char*)sB + dsOf[r]) = rb[r];
            }
            asm volatile("s_waitcnt lgkmcnt(0)" ::: "memory");   // my ds_writes done
            __builtin_amdgcn_s_barrier();                        // writes visible
            asm volatile("" ::: "memory");
            // issue loads for tile t+2 AFTER the barrier: they stay in flight
            // across compute(t+1) + barrier, consumed at the next ds_write.
            if (t + 2 < nt) {
                const int k0 = (t + 2) * 64;
                #pragma unroll
                for (int r = 0; r < 2; ++r) {
                    ra[r] = *(const short8*)(A + aRow[r] + k0);
                    rb[r] = *(const short8*)(Bw + bRow[r] + k0);
                }
            }
        }
    }

    // epilogue: C/D layout col=lane&15, row=(lane>>4)*4+reg (m89-verified)
    const int cl = lane & 15;
    const int rg = (lane >> 4) * 4;
    #pragma unroll
    for (int j2 = 0; j2 < 4; ++j2) {
        const int col = n0 + wn * 64 + j2 * 16 + cl;
        const float bv = bias[col];
        #pragma unroll
        for (int i = 0; i < 2; ++i) {
            #pragma unroll
            for (int r = 0; r < 4; ++r) {
                const int rowg = m0 + wm * 32 + i * 16 + rg + r;
                float v = acc[i][j2][r] + bv;
                if (ACT) v = softplus_f(v);
                C[(size_t)rowg * N + col] = v;
            }
        }
    }
}

// ---------------- scan phase 1: per-chunk local scan (zero init) ----------------
__global__ __launch_bounds__(256) void scan_p1(const float* __restrict__ delta,
                                               const float* __restrict__ x,
                                               const float* __restrict__ a_log,
                                               float* __restrict__ S,       // [NCH,B,D,N]
                                               float* __restrict__ dtsum) { // [NCH,B,D]
    const int gid = blockIdx.x * 256 + threadIdx.x;
    const int d = gid & (D_ - 1);
    const int cb = gid >> 10;
    const int b = cb & (B_ - 1);
    const int c = cb >> 2;

    float an2[N_];
    const float4* a4 = (const float4*)&a_log[d * N_];
    #pragma unroll
    for (int q = 0; q < 4; ++q) {
        float4 av = a4[q];
        an2[q * 4 + 0] = (softplus_f(av.x) + 1e-4f) * 1.44269504f;
        an2[q * 4 + 1] = (softplus_f(av.y) + 1e-4f) * 1.44269504f;
        an2[q * 4 + 2] = (softplus_f(av.z) + 1e-4f) * 1.44269504f;
        an2[q * 4 + 3] = (softplus_f(av.w) + 1e-4f) * 1.44269504f;
    }

    float s[N_];
    #pragma unroll
    for (int n = 0; n < N_; ++n) s[n] = 0.f;
    float dts = 0.f;

    const size_t base = ((size_t)b * T_ + (size_t)c * TCH) * D_ + d;
    for (int i = 0; i < TCH; ++i) {
        const float dt = delta[base + (size_t)i * D_];
        const float xv = x[base + (size_t)i * D_];
        const float dtx = dt * xv;
        dts += dt;
        #pragma unroll
        for (int n = 0; n < N_; ++n) {
            const float ab = EXP2(-dt * an2[n]);
            s[n] = fmaf(ab, s[n], dtx);
        }
    }

    float* So = &S[(size_t)gid * N_];
    #pragma unroll
    for (int n = 0; n < N_; ++n) So[n] = s[n];
    dtsum[gid] = dts;
}

// ---------------- scan phase 2: 64-step carry scan across chunks ----------------
__global__ __launch_bounds__(256) void scan_p2(const float* __restrict__ S,
                                               const float* __restrict__ dtsum,
                                               const float* __restrict__ a_log,
                                               float* __restrict__ carry_out) {
    const int gid = blockIdx.x * 256 + threadIdx.x;
    const int n = gid & 15;
    const int d = (gid >> 4) & (D_ - 1);
    const int b = gid >> 14;
    const float an2 = (softplus_f(a_log[d * N_ + n]) + 1e-4f) * 1.44269504f;
    float carry = 0.f;
    for (int c = 0; c < NCH; ++c) {
        const size_t cb = (size_t)c * B_ + b;
        const size_t idx = (cb * D_ + d) * N_ + n;
        carry_out[idx] = carry;                       // carry INTO chunk c
        const float dts = dtsum[cb * D_ + d];
        const float P = EXP2(-dts * an2);             // prod of a_bar over chunk
        carry = fmaf(P, carry, S[idx]);
    }
}

// ---------------- scan phase 3: replay with true carry, emit y (bf16) ----------------
__global__ __launch_bounds__(256) void scan_p3(const float* __restrict__ delta,
                                               const float* __restrict__ x,
                                               const float* __restrict__ a_log,
                                               const float* __restrict__ b_param,
                                               const float* __restrict__ carry_in,
                                               u16* __restrict__ y) {  // [B,T,D] bf16
    const int gid = blockIdx.x * 256 + threadIdx.x;
    const int d = gid & (D_ - 1);
    const int cb = gid >> 10;
    const int b = cb & (B_ - 1);
    const int c = cb >> 2;

    float an2[N_], bp[N_];
    const float4* a4 = (const float4*)&a_log[d * N_];
    const float4* b4 = (const float4*)&b_param[d * N_];
    #pragma unroll
    for (int q = 0; q < 4; ++q) {
        float4 av = a4[q];
        float4 bv = b4[q];
        an2[q * 4 + 0] = (softplus_f(av.x) + 1e-4f) * 1.44269504f;
        an2[q * 4 + 1] = (softplus_f(av.y) + 1e-4f) * 1.44269504f;
        an2[q * 4 + 2] = (softplus_f(av.z) + 1e-4f) * 1.44269504f;
        an2[q * 4 + 3] = (softplus_f(av.w) + 1e-4f) * 1.44269504f;
        bp[q * 4 + 0] = bv.x; bp[q * 4 + 1] = bv.y;
        bp[q * 4 + 2] = bv.z; bp[q * 4 + 3] = bv.w;
    }

    float s[N_];
    const float* ci = &carry_in[(size_t)gid * N_];
    #pragma unroll
    for (int n = 0; n < N_; ++n) s[n] = ci[n];

    const size_t base = ((size_t)b * T_ + (size_t)c * TCH) * D_ + d;
    for (int i = 0; i < TCH; ++i) {
        const float dt = delta[base + (size_t)i * D_];
        const float xv = x[base + (size_t)i * D_];
        const float dtx = dt * xv;
        float acc = 0.f;
        #pragma unroll
        for (int n = 0; n < N_; ++n) {
            const float ab = EXP2(-dt * an2[n]);
            s[n] = fmaf(ab, s[n], dtx);
            acc = fmaf(bp[n], s[n], acc);
        }
        y[base + (size_t)i * D_] = f2bf(acc);
    }
}

// ---------------- launch ----------------
extern "C" void kernel_launch(void* const* d_in, const int* in_sizes, int n_in,
                              void* d_out, int out_size, void* d_ws, size_t ws_size,
                              hipStream_t stream) {
    const float* x      = (const float*)d_in[0];
    const float* Wd     = (const float*)d_in[1];
    const float* bd     = (const float*)d_in[2];
    const float* a_log  = (const float*)d_in[3];
    const float* b_par  = (const float*)d_in[4];
    const float* Wo     = (const float*)d_in[5];
    const float* bo     = (const float*)d_in[6];
    float* out = (float*)d_out;

    char* ws = (char*)d_ws;
    // region A (16 MB): x_bf16 during GEMM1, then carry_in for scan p2/p3
    u16*   xbf     = (u16*)(ws);
    float* carry   = (float*)(ws);
    // region B (16 MB): S during p1/p2, then y_bf16 for p3/GEMM2
    float* S       = (float*)(ws + 16777216);
    u16*   ybf     = (u16*)(ws + 16777216);
    float* delta   = (float*)(ws + 33554432);          // 32 MB
    u16*   wdbf    = (u16*)(ws + 67108864);            // 2 MB
    u16*   wobf    = (u16*)(ws + 69206016);            // 2 MB
    float* dtsum   = (float*)(ws + 71303168);          // 1 MB
    (void)in_sizes; (void)n_in; (void)out_size; (void)ws_size;

    const int M = B_ * T_;  // 8192

    // convert inputs to bf16
    cvt_f32_bf16<<<(M * D_ / 4 + 255) / 256, 256, 0, stream>>>(x, xbf, M * D_ / 4);
    cvt_f32_bf16<<<(D_ * D_ / 4 + 255) / 256, 256, 0, stream>>>(Wd, wdbf, D_ * D_ / 4);
    cvt_f32_bf16<<<(D_ * D_ / 4 + 255) / 256, 256, 0, stream>>>(Wo, wobf, D_ * D_ / 4);

    // delta = softplus(x @ Wd^T + bd)
    gemm_bt<1><<<(M / 128) * (D_ / 128), 512, 0, stream>>>(xbf, wdbf, bd, delta, M, D_, D_);

    // blocked scan
    scan_p1<<<NCH * B_ * D_ / 256, 256, 0, stream>>>(delta, x, a_log, S, dtsum);
    scan_p2<<<B_ * D_ * N_ / 256, 256, 0, stream>>>(S, dtsum, a_log, carry);
    scan_p3<<<NCH * B_ * D_ / 256, 256, 0, stream>>>(delta, x, a_log, b_par, carry, ybf);

    // out = y @ Wo^T + bo
    gemm_bt<0><<<(M / 128) * (D_ / 128), 512, 0, stream>>>(ybf, wobf, bo, out, M, D_, D_);
}